// Round 7
// baseline (236.618 us; speedup 1.0000x reference)
//
#include <hip/hip_runtime.h>

#define GLOBAL_AS __attribute__((address_space(1)))
#define LDS_AS __attribute__((address_space(3)))

typedef unsigned short u16;
typedef unsigned int u32;
typedef __bf16 bf16x8 __attribute__((ext_vector_type(8)));
typedef float f32x4 __attribute__((ext_vector_type(4)));

static constexpr int BB = 8;        // batch
static constexpr int TT = 2048;     // time
static constexpr int DD = 1024;     // feature dim
static constexpr int MM = BB * TT;  // 16384 rows
static constexpr int KK = DD;       // 1024
static constexpr int NC = 64;       // scan chunks per sequence
static constexpr int CL = TT / NC;  // 32 timesteps per chunk
static constexpr int NCH = BB * NC; // 512 total chunks

__device__ __forceinline__ u16 f2bf(float f) {
  union { float f; u32 u; } c; c.f = f;
  u32 u = c.u;
  u32 r = (u + 0x7fffu + ((u >> 16) & 1u)) >> 16;  // RNE
  return (u16)r;
}

__device__ __forceinline__ float bf2f(u16 b) {
  union { u32 u; float f; } c; c.u = ((u32)b) << 16;
  return c.f;
}

// ---------------- pass 0: fused converts (x fp32->bf16 ; W fp32->bf16 W^T) ----------
// One kernel, grid-partitioned: blocks [0,8192) convert x (8 elems/thread),
// blocks [8192,10240) transpose-convert Wz/Wh. Saves a launch + tail vs 2 kernels.
__global__ __launch_bounds__(256) void cvt_fused_kernel(
    const float* __restrict__ x, u16* __restrict__ xb,
    const float* __restrict__ Wz, const float* __restrict__ Wh,
    u16* __restrict__ WT) {
  int bid = blockIdx.x;
  int tid = threadIdx.x;
  if (bid < 8192) {
    int i = (bid * 256 + tid) * 8;
    const float4* p = reinterpret_cast<const float4*>(x + i);
    float4 v0 = p[0], v1 = p[1];
    uint4 o;
    o.x = (u32)f2bf(v0.x) | ((u32)f2bf(v0.y) << 16);
    o.y = (u32)f2bf(v0.z) | ((u32)f2bf(v0.w) << 16);
    o.z = (u32)f2bf(v1.x) | ((u32)f2bf(v1.y) << 16);
    o.w = (u32)f2bf(v1.z) | ((u32)f2bf(v1.w) << 16);
    *reinterpret_cast<uint4*>(xb + i) = o;
  } else {
    __shared__ float tile[32][33];
    int wid = bid - 8192;           // 0..2047
    int w = wid >> 10;              // 0..1 (Wz / Wh)
    int r = wid & 1023;             // 0..1023 -> 32x32 tile grid
    int n0 = (r & 31) * 32;
    int k0 = (r >> 5) * 32;
    const float* W = w ? Wh : Wz;
    u16* O = WT + (size_t)w * DD * KK;
    int tx = tid & 31, ty = tid >> 5;   // 32 x 8
    for (int i = 0; i < 32; i += 8)
      tile[ty + i][tx] = W[(size_t)(k0 + ty + i) * DD + n0 + tx];
    __syncthreads();
    for (int i = 0; i < 32; i += 8)
      O[(size_t)(n0 + ty + i) * KK + k0 + tx] = f2bf(tile[tx][ty + i]);
  }
}

// ---------------- pass 1: dual GEMM + gate epilogue + fused chunk-reduce ----------------
// VERIFIED structure (r4/r6): ~81us, MfmaUtil 37%, 0 bank conflicts, no spill.
// (rule #20 lesson: every loop touching accz/acch/Ai/Bi MUST be #pragma unroll --
//  a runtime acc index demotes the whole accumulator to scratch: 2.3GB WRITE_SIZE.)
// DO NOT restructure the main loop (double-buffer regressed via regalloc, r2).
// Packs (a fixed-u16 | b bf16); summaries composed from ROUNDED values so the
// downstream scan/reader are self-consistent.
__global__ __launch_bounds__(256, 2) void gemm_dual_kernel(
    const u16* __restrict__ xb,   // [MM][KK] bf16
    const u16* __restrict__ WT,   // [2][DD][KK] bf16 (n-major)
    const float* __restrict__ bz, const float* __restrict__ bh,
    u32* __restrict__ ab_out,     // [MM][DD] packed: lo16 = a*65535, hi16 = bf16(b)
    float* __restrict__ Asum, float* __restrict__ Bsum) {
  __shared__ __align__(16) u16 As[128 * 64];
  __shared__ __align__(16) u16 Bzs[128 * 64];
  __shared__ __align__(16) u16 Bhs[128 * 64];

  // XCD-aware swizzle: bid -> swz so XCD x (bid%8==x) gets contiguous swz chunk
  int bid = blockIdx.x;
  int swz = ((bid & 7) << 7) | (bid >> 3);   // bijective (bit permutation)
  int mt = swz >> 3;    // 128 m-tiles
  int nt = swz & 7;     // 8 n-tiles of 128
  int m0 = mt * 128, n0 = nt * 128;

  int tid = threadIdx.x;
  int lane = tid & 63;
  int wave = tid >> 6;
  int wr = wave >> 1;   // wave row 0..1  (owns rows wr*64..wr*64+63)
  int wc = wave & 1;    // wave col 0..1  (owns cols wc*64..wc*64+63)

  // staging: thread's linear LDS dest for issue q is byte  tid*16 + q*4096
  //   -> row r = (tid>>3) + q*32, col-byte = (tid&7)*16, then inverse-swizzled.
  int r0 = tid >> 3;                                    // 0..31
  int cswz = ((tid & 7) ^ ((tid >> 3) & 7)) << 3;       // swizzled col (elems)
  const u16* Ag  = xb + (size_t)(m0 + r0) * KK + cswz;
  const u16* Bzg = WT + (size_t)(n0 + r0) * KK + cswz;
  const u16* Bhg = Bzg + (size_t)DD * KK;

  u16* AsW  = As  + wave * 512;   // wave-uniform base; HW adds lane*16B
  u16* BzsW = Bzs + wave * 512;
  u16* BhsW = Bhs + wave * 512;

  f32x4 accz[4][4];   // [i: 16-row frag][j: 16-col frag]
  f32x4 acch[4][4];
#pragma unroll
  for (int i = 0; i < 4; i++)
#pragma unroll
    for (int j = 0; j < 4; j++) {
      accz[i][j] = (f32x4){0.f, 0.f, 0.f, 0.f};
      acch[i][j] = (f32x4){0.f, 0.f, 0.f, 0.f};
    }

  int fr = lane & 15;
  int fk = (lane >> 4) * 8;
  const int swx = (fr & 7) << 3;   // read-side XOR (elems); row&7 == fr&7 here

  for (int k0i = 0; k0i < KK; k0i += 64) {
#pragma unroll
    for (int q = 0; q < 4; q++) {
      __builtin_amdgcn_global_load_lds((const GLOBAL_AS void*)(Ag  + k0i + (size_t)(q * 32) * KK),
                                       (LDS_AS void*)(AsW + q * 2048), 16, 0, 0);
      __builtin_amdgcn_global_load_lds((const GLOBAL_AS void*)(Bzg + k0i + (size_t)(q * 32) * KK),
                                       (LDS_AS void*)(BzsW + q * 2048), 16, 0, 0);
      __builtin_amdgcn_global_load_lds((const GLOBAL_AS void*)(Bhg + k0i + (size_t)(q * 32) * KK),
                                       (LDS_AS void*)(BhsW + q * 2048), 16, 0, 0);
    }
    __syncthreads();  // drains vmcnt -> staging visible

#pragma unroll
    for (int kk = 0; kk < 64; kk += 32) {
      bf16x8 af[4], bzf[4], bhf[4];
#pragma unroll
      for (int i = 0; i < 4; i++)
        af[i] = *reinterpret_cast<const bf16x8*>(
            As + (wr * 64 + i * 16 + fr) * 64 + ((kk + fk) ^ swx));
#pragma unroll
      for (int j = 0; j < 4; j++) {
        int br = wc * 64 + j * 16 + fr;
        bzf[j] = *reinterpret_cast<const bf16x8*>(Bzs + br * 64 + ((kk + fk) ^ swx));
        bhf[j] = *reinterpret_cast<const bf16x8*>(Bhs + br * 64 + ((kk + fk) ^ swx));
      }
#pragma unroll
      for (int i = 0; i < 4; i++)
#pragma unroll
        for (int j = 0; j < 4; j++) {
          accz[i][j] = __builtin_amdgcn_mfma_f32_16x16x32_bf16(af[i], bzf[j], accz[i][j], 0, 0, 0);
          acch[i][j] = __builtin_amdgcn_mfma_f32_16x16x32_bf16(af[i], bhf[j], acch[i][j], 0, 0, 0);
        }
    }
    __syncthreads();  // tiles consumed before restage
  }

  // epilogue: D[row = m0 + wr*64 + i*16 + quad*4 + r][col = n0 + wc*64 + j*16 + fr]
  // wave owns 64 rows = 2 scan chunks (CL=32): chunk ic composed from i=2ic,2ic+1
  int quad = lane >> 4;
#pragma unroll
  for (int j = 0; j < 4; j++) {
    int n = n0 + wc * 64 + j * 16 + fr;
    float bzv = bz[n], bhv = bh[n];
    float Ai[4], Bi[4];
#pragma unroll
    for (int i = 0; i < 4; i++) {
      float Aloc = 1.f, Bloc = 0.f;
      int mbase = m0 + wr * 64 + i * 16 + quad * 4;
#pragma unroll
      for (int r = 0; r < 4; r++) {
        float zp = accz[i][j][r] + bzv;
        float hp = acch[i][j][r] + bhv;
        float zs = 1.0f / (1.0f + __expf(-zp));
        float av = 1.0f - zs;
        float bv = zs * hp;
        // pack: a as 16-bit fixed point (err 1.5e-5), b as bf16
        u32 aq = (u32)(av * 65535.0f + 0.5f);
        if (aq > 65535u) aq = 65535u;
        u16 bb16 = f2bf(bv);
        size_t idx = (size_t)(mbase + r) * DD + n;
        ab_out[idx] = aq | ((u32)bb16 << 16);
        // compose from the ROUNDED values (consistent with pass 2's reader)
        float avr = (float)aq * (1.0f / 65535.0f);
        float bvr = bf2f(bb16);
        Bloc = avr * Bloc + bvr;   // t-ascending composition
        Aloc = avr * Aloc;
      }
      // ordered cross-quad combine (quads hold rows quad*4..quad*4+3 in the 16-row frag)
      float Ao = __shfl_xor(Aloc, 16, 64);
      float Bo = __shfl_xor(Bloc, 16, 64);
      float Bc = (quad & 1) ? (Aloc * Bo + Bloc) : (Ao * Bloc + Bo);
      float Ac = Aloc * Ao;
      float Ao2 = __shfl_xor(Ac, 32, 64);
      float Bo2 = __shfl_xor(Bc, 32, 64);
      Bi[i] = (quad & 2) ? (Ac * Bo2 + Bc) : (Ao2 * Bc + Bo2);
      Ai[i] = Ac * Ao2;
    }
    // chunk summaries: ic=0 -> frags i0,i1 (rows 0..31), ic=1 -> frags i2,i3
#pragma unroll
    for (int ic = 0; ic < 2; ic++) {
      float Ack = Ai[2 * ic + 1] * Ai[2 * ic];
      float Bck = Ai[2 * ic + 1] * Bi[2 * ic] + Bi[2 * ic + 1];
      if (quad == 0) {
        int cg = mt * 4 + wr * 2 + ic;   // global chunk id = (m0 + wr*64 + ic*32)/32
        Asum[(size_t)cg * DD + n] = Ack;
        Bsum[(size_t)cg * DD + n] = Bck;
      }
    }
  }
}

// ---------------- pass 2: FUSED chunk-scan prologue + recurrence + swish + LN ---------
// Round-4 structure for the t-loop (PROVEN: 4 waves/block, 512 blocks = 2 blocks/CU,
// all co-resident; r5's wave-per-chunk capped waves at 0.5/SIMD and lost 32us).
// NEW: the chunk_scan kernel is gone -- each block rebuilds its own h_in by
// scanning Asum/Bsum rows 0..c-1 for its d-slice in the prologue (<=63 dependent
// FMA4 steps; the 2MB summary arrays are L2/L3-resident; loads are independent so
// they pipeline under the chain). Same composition order as the old kernel ->
// bit-identical h_in. Saves a launch, the 32-block latency-bound scan kernel,
// and the hin round-trip.
__global__ __launch_bounds__(256) void apply_ln_kernel(
    const u32* __restrict__ ab,
    const float* __restrict__ Asum, const float* __restrict__ Bsum,
    const float* __restrict__ sbeta, const float* __restrict__ gamma,
    const float* __restrict__ lbeta, float* __restrict__ out) {
  __shared__ float ps[2][4];
  __shared__ float pq[2][4];
  int ch = blockIdx.x;                 // chunk id 0..511
  int wv = threadIdx.x >> 6;
  int lane = threadIdx.x & 63;
  int d = wv * 256 + lane * 4;
  int b = ch >> 6, c = ch & (NC - 1);
  float sb = sbeta[0];

  float4 g4 = *reinterpret_cast<const float4*>(gamma + d);
  float4 be4 = *reinterpret_cast<const float4*>(lbeta + d);

  // fused chunk scan: h = compose(chunks 0..c-1) applied to h0=0, this d-slice
  float4 h4 = {0.f, 0.f, 0.f, 0.f};
  {
    size_t srow = ((size_t)b * NC) * DD + d;   // + cc*DD
#pragma unroll 4
    for (int cc = 0; cc < c; cc++) {
      float4 av = *reinterpret_cast<const float4*>(Asum + srow + (size_t)cc * DD);
      float4 bv = *reinterpret_cast<const float4*>(Bsum + srow + (size_t)cc * DD);
      h4.x = av.x * h4.x + bv.x;
      h4.y = av.y * h4.y + bv.y;
      h4.z = av.z * h4.z + bv.z;
      h4.w = av.w * h4.w + bv.w;
    }
  }

  size_t base = ((size_t)b * TT + (size_t)c * CL) * DD + d;  // + t*DD

  // depth-3 prefetch ring (statically indexed after full unroll)
  uint4 zR[3];
#pragma unroll
  for (int p = 0; p < 3; p++)
    zR[p] = *reinterpret_cast<const uint4*>(ab + base + (size_t)p * DD);

#pragma unroll
  for (int t = 0; t < CL; t++) {
    const int slot = t % 3;
    const int pslot = t & 1;
    uint4 pv = zR[slot];
    if (t + 3 < CL)   // refill ring; overlaps the math below
      zR[slot] = *reinterpret_cast<const uint4*>(ab + base + (size_t)(t + 3) * DD);
    // unpack + recurrence: h = a*h + b   (a = lo16/65535, b = bf16 in hi16)
    {
      union { u32 u; float f; } cb;
      const float as = 1.0f / 65535.0f;
      float av;
      av = (float)(pv.x & 0xffffu) * as; cb.u = pv.x & 0xffff0000u;
      h4.x = av * h4.x + cb.f;
      av = (float)(pv.y & 0xffffu) * as; cb.u = pv.y & 0xffff0000u;
      h4.y = av * h4.y + cb.f;
      av = (float)(pv.z & 0xffffu) * as; cb.u = pv.z & 0xffff0000u;
      h4.z = av * h4.z + cb.f;
      av = (float)(pv.w & 0xffffu) * as; cb.u = pv.w & 0xffff0000u;
      h4.w = av * h4.w + cb.f;
    }
    float sx = sb * h4.x, sy = sb * h4.y, sz = sb * h4.z, sw = sb * h4.w;
    float4 y;
    y.x = sx / (1.0f + __expf(-sx));
    y.y = sy / (1.0f + __expf(-sy));
    y.z = sz / (1.0f + __expf(-sz));
    y.w = sw / (1.0f + __expf(-sw));
    float sum = y.x + y.y + y.z + y.w;
    float sq = y.x * y.x + y.y * y.y + y.z * y.z + y.w * y.w;
#pragma unroll
    for (int o = 32; o > 0; o >>= 1) {
      sum += __shfl_xor(sum, o, 64);
      sq += __shfl_xor(sq, o, 64);
    }
    if (lane == 0) { ps[pslot][wv] = sum; pq[pslot][wv] = sq; }
    __syncthreads();
    float tot = ps[pslot][0] + ps[pslot][1] + ps[pslot][2] + ps[pslot][3];
    float totq = pq[pslot][0] + pq[pslot][1] + pq[pslot][2] + pq[pslot][3];
    float mu = tot * (1.0f / DD);
    float var = totq * (1.0f / DD) - mu * mu;
    float inv = rsqrtf(fmaxf(var, 0.f) + 1e-5f);
    float4 o4;
    o4.x = (y.x - mu) * inv * g4.x + be4.x;
    o4.y = (y.y - mu) * inv * g4.y + be4.y;
    o4.z = (y.z - mu) * inv * g4.z + be4.z;
    o4.w = (y.w - mu) * inv * g4.w + be4.w;
    *reinterpret_cast<float4*>(out + base + (size_t)t * DD) = o4;
  }
}

extern "C" void kernel_launch(void* const* d_in, const int* in_sizes, int n_in,
                              void* d_out, int out_size, void* d_ws, size_t ws_size,
                              hipStream_t stream) {
  const float* x     = (const float*)d_in[0];
  const float* Wz    = (const float*)d_in[1];
  const float* bz    = (const float*)d_in[2];
  const float* Wh    = (const float*)d_in[3];
  const float* bh    = (const float*)d_in[4];
  const float* sbeta = (const float*)d_in[5];
  const float* gamma = (const float*)d_in[6];
  const float* lbeta = (const float*)d_in[7];
  float* out = (float*)d_out;

  char* ws = (char*)d_ws;
  u16* xb     = (u16*)ws;                         // 33,554,432 B
  u16* WT     = (u16*)(ws + 33554432);            //  4,194,304 B
  u32* ab     = (u32*)(ws + 37748736);            // 67,108,864 B (packed a|b)
  float* Asum = (float*)(ws + 104857600);         //  2,097,152 B
  float* Bsum = (float*)(ws + 106954752);         //  2,097,152 B  (total 109,051,904)

  cvt_fused_kernel<<<10240, 256, 0, stream>>>(x, xb, Wz, Wh, WT);
  gemm_dual_kernel<<<1024, 256, 0, stream>>>(xb, WT, bz, bh, ab, Asum, Bsum);
  apply_ln_kernel<<<NCH, 256, 0, stream>>>(ab, Asum, Bsum, sbeta, gamma, lbeta, out);
}